// Round 1
// 190.121 us; speedup vs baseline: 1.1382x; 1.1382x over previous
//
#include <hip/hip_runtime.h>
#include <hip/hip_bf16.h>

#define N_NODES 50000
#define N_EDGES 800000
#define EMB 64
#define HID 64
#define N_CLASSES 10
#define N_GRAPHS 512

#define BKT_SHIFT 6
#define BKT_NODES 64
#define NB_BKT ((N_NODES + BKT_NODES - 1) / BKT_NODES)   // 782
#define BKT_CAP 1408     // mean 1024 + 12 sigma
#define CNT_STRIDE 16    // one counter per 64B line: kills cross-XCD false sharing
#define EB_CHUNK 4096
#define EB_BLOCKS ((N_EDGES + EB_CHUNK - 1) / EB_CHUNK)  // 196
#define XFORM_BLOCKS ((N_NODES + 63) / 64)               // 782
#define XPAD 68

// bf16 row accumulate: 8 bf16 dims (uint4) into fp32[8]
#define ACC8(vv, A)                                                            \
    do {                                                                       \
        A[0] += __uint_as_float((vv).x << 16);                                 \
        A[1] += __uint_as_float((vv).x & 0xFFFF0000u);                         \
        A[2] += __uint_as_float((vv).y << 16);                                 \
        A[3] += __uint_as_float((vv).y & 0xFFFF0000u);                         \
        A[4] += __uint_as_float((vv).z << 16);                                 \
        A[5] += __uint_as_float((vv).z & 0xFFFF0000u);                         \
        A[6] += __uint_as_float((vv).w << 16);                                 \
        A[7] += __uint_as_float((vv).w & 0xFFFF0000u);                         \
    } while (0)

// Build this bucket's CSR in LDS from its ebuf region. All 256 threads.
// Scan: BKT_NODES == 64 == wave size -> wave0 shfl scan, 4 barriers total.
__device__ __forceinline__ void build_local_csr(
    int bucket, const int* __restrict__ cnt, const int* __restrict__ ebuf,
    unsigned short* lcsr, int* nhist, int* sval, int* sexcl, int* ncur) {
    int tid = threadIdx.x;
    int bs = bucket * BKT_CAP;
    int ne = min(cnt[bucket * CNT_STRIDE], BKT_CAP);   // defensive clamp
    if (tid < BKT_NODES) { nhist[tid] = 0; ncur[tid] = 0; }
    __syncthreads();
    for (int i = tid; i < ne; i += 256)
        atomicAdd(&nhist[ebuf[bs + i] >> 16], 1);
    __syncthreads();
    if (tid < 64) {            // wave 0: inclusive scan via shfl_up
        int v = nhist[tid];
        int s = v;
#pragma unroll
        for (int off = 1; off < 64; off <<= 1) {
            int u = __shfl_up(s, off, 64);
            if (tid >= off) s += u;
        }
        sval[tid] = v;
        sexcl[tid] = s - v;
    }
    __syncthreads();
    for (int i = tid; i < ne; i += 256) {
        int p = ebuf[bs + i];
        int l = p >> 16;
        int r = atomicAdd(&ncur[l], 1);
        lcsr[sexcl[l] + r] = (unsigned short)(p & 0xFFFF);
    }
    __syncthreads();
}

// Dual-node mean aggregation: both nodes' chunks in flight (16 outstanding
// 16B gathers) to double memory-level parallelism vs sequential nodes.
__device__ __forceinline__ void agg2(
    int sA, int dA, int sB, int dB, int sl,
    const unsigned short* lcsr, const __hip_bfloat16* __restrict__ Pb,
    float oA[8], float oB[8]) {
    float a0[8], a1[8], b0[8], b1[8];
#pragma unroll
    for (int j = 0; j < 8; j++) { a0[j] = 0.f; a1[j] = 0.f; b0[j] = 0.f; b1[j] = 0.f; }
    int eA = sA + dA, eB = sB + dB;
    int pA = sA, pB = sB;
    while ((pA + 8 <= eA) && (pB + 8 <= eB)) {
        uint4 vA[8], vB[8];
#pragma unroll
        for (int j = 0; j < 8; j++)
            vA[j] = ((const uint4*)(Pb + (size_t)lcsr[pA + j] * 64))[sl];
#pragma unroll
        for (int j = 0; j < 8; j++)
            vB[j] = ((const uint4*)(Pb + (size_t)lcsr[pB + j] * 64))[sl];
#pragma unroll
        for (int j = 0; j < 8; j++) ACC8(vA[j], ((j & 1) ? a1 : a0));
#pragma unroll
        for (int j = 0; j < 8; j++) ACC8(vB[j], ((j & 1) ? b1 : b0));
        pA += 8; pB += 8;
    }
    while (pA + 8 <= eA) {
        uint4 v[8];
#pragma unroll
        for (int j = 0; j < 8; j++)
            v[j] = ((const uint4*)(Pb + (size_t)lcsr[pA + j] * 64))[sl];
#pragma unroll
        for (int j = 0; j < 8; j++) ACC8(v[j], ((j & 1) ? a1 : a0));
        pA += 8;
    }
    while (pB + 8 <= eB) {
        uint4 v[8];
#pragma unroll
        for (int j = 0; j < 8; j++)
            v[j] = ((const uint4*)(Pb + (size_t)lcsr[pB + j] * 64))[sl];
#pragma unroll
        for (int j = 0; j < 8; j++) ACC8(v[j], ((j & 1) ? b1 : b0));
        pB += 8;
    }
    for (; pA < eA; ++pA) {
        uint4 v = ((const uint4*)(Pb + (size_t)lcsr[pA] * 64))[sl];
        ACC8(v, a0);
    }
    for (; pB < eB; ++pB) {
        uint4 v = ((const uint4*)(Pb + (size_t)lcsr[pB] * 64))[sl];
        ACC8(v, b0);
    }
    float invA = (dA > 0) ? 1.0f / (float)dA : 0.0f;
    float invB = (dB > 0) ? 1.0f / (float)dB : 0.0f;
#pragma unroll
    for (int j = 0; j < 8; j++) {
        oA[j] = (a0[j] + a1[j]) * invA;
        oB[j] = (b0[j] + b1[j]) * invB;
    }
}

// m += Q (from H), relu, stage 8 dims into dst[sl*8..sl*8+7]
__device__ __forceinline__ void finish_row(int node, int sl,
                                           const float* __restrict__ H,
                                           float m[8], float* dst) {
    if (node < N_NODES) {
        size_t off = (size_t)node * 64 + sl * 8;
        float4 q0 = *(const float4*)&H[off];
        float4 q1 = *(const float4*)&H[off + 4];
        m[0] = fmaxf(m[0] + q0.x, 0.f);
        m[1] = fmaxf(m[1] + q0.y, 0.f);
        m[2] = fmaxf(m[2] + q0.z, 0.f);
        m[3] = fmaxf(m[3] + q0.w, 0.f);
        m[4] = fmaxf(m[4] + q1.x, 0.f);
        m[5] = fmaxf(m[5] + q1.y, 0.f);
        m[6] = fmaxf(m[6] + q1.z, 0.f);
        m[7] = fmaxf(m[7] + q1.w, 0.f);
    } else {
#pragma unroll
        for (int j = 0; j < 8; j++) m[j] = 0.f;
    }
    *(float4*)&dst[sl * 8] = make_float4(m[0], m[1], m[2], m[3]);
    *(float4*)&dst[sl * 8 + 4] = make_float4(m[4], m[5], m[6], m[7]);
}

// ---------------- combo: bucket multi-split (blocks 0..EB) + layer-0 xform ----------------
__global__ __launch_bounds__(256) void k_combo(
    const int* __restrict__ esrc, const int* __restrict__ edst,
    int* __restrict__ cnt, int* __restrict__ ebuf,
    const int* __restrict__ ids, const float* __restrict__ emb,
    const float* __restrict__ Wl, const float* __restrict__ bl,
    const float* __restrict__ Wr,
    __hip_bfloat16* __restrict__ Pb, float* __restrict__ Qout) {
    __shared__ float sW[64 * 64];
    __shared__ float sX[64 * XPAD];
    int t = threadIdx.x;
    if (blockIdx.x < EB_BLOCKS) {
        // ---- bsplit path: alias LDS as int scratch ----
        int* h = (int*)sW;                 // NB_BKT
        int* bbase = h + NB_BKT;           // NB_BKT
        int* cur = (int*)sX;               // NB_BKT
        for (int i = t; i < NB_BKT; i += 256) { h[i] = 0; cur[i] = 0; }
        __syncthreads();
        int base = blockIdx.x * EB_CHUNK;
        int end = min(base + EB_CHUNK, N_EDGES);
        for (int i = base + t; i < end; i += 256)
            atomicAdd(&h[edst[i] >> BKT_SHIFT], 1);
        __syncthreads();
        for (int i = t; i < NB_BKT; i += 256)
            if (h[i]) bbase[i] = i * BKT_CAP + atomicAdd(&cnt[i * CNT_STRIDE], h[i]);
        __syncthreads();
        for (int i = base + t; i < end; i += 256) {
            int d = edst[i], s = esrc[i];
            int b = d >> BKT_SHIFT;
            int r = atomicAdd(&cur[b], 1);
            int slot = bbase[b] + r;
            if (slot < (b + 1) * BKT_CAP)          // defensive clamp
                ebuf[slot] = ((d & (BKT_NODES - 1)) << 16) | s;
        }
        return;
    }
    // ---- xform0 path (two-pass W staging) ----
    int tile = (blockIdx.x - EB_BLOCKS) * 64;
    for (int i = t; i < 64 * 16; i += 256)
        ((float4*)sW)[i] = ((const float4*)Wl)[i];
    for (int i = t; i < 64 * 16; i += 256) {
        int r = i >> 4, c = i & 15;
        int node = tile + r;
        float4 v = make_float4(0.f, 0.f, 0.f, 0.f);
        if (node < N_NODES)
            v = ((const float4*)(emb + (size_t)ids[node] * 64))[c];
        *(float4*)&sX[r * XPAD + c * 4] = v;
    }
    __syncthreads();
    int dg = t & 15, ng = t >> 4;
    float acc[4][4];
#pragma unroll
    for (int i = 0; i < 4; i++)
#pragma unroll
        for (int j = 0; j < 4; j++) acc[i][j] = 0.f;
#pragma unroll 4
    for (int k = 0; k < 64; k++) {
        float4 w = *(const float4*)&sW[k * 64 + dg * 4];
#pragma unroll
        for (int i = 0; i < 4; i++) {
            float xv = sX[(ng + i * 16) * XPAD + k];
            acc[i][0] = fmaf(xv, w.x, acc[i][0]);
            acc[i][1] = fmaf(xv, w.y, acc[i][1]);
            acc[i][2] = fmaf(xv, w.z, acc[i][2]);
            acc[i][3] = fmaf(xv, w.w, acc[i][3]);
        }
    }
#pragma unroll
    for (int i = 0; i < 4; i++) {
        int node = tile + ng + i * 16;
        if (node < N_NODES) {
            union { ushort4 u; __hip_bfloat16 h[4]; } pk;
            pk.h[0] = __float2bfloat16(acc[i][0]);
            pk.h[1] = __float2bfloat16(acc[i][1]);
            pk.h[2] = __float2bfloat16(acc[i][2]);
            pk.h[3] = __float2bfloat16(acc[i][3]);
            *(ushort4*)&Pb[(size_t)node * 64 + dg * 4] = pk.u;
        }
    }
    __syncthreads();
    for (int i = t; i < 64 * 16; i += 256)
        ((float4*)sW)[i] = ((const float4*)Wr)[i];
    __syncthreads();
#pragma unroll
    for (int i = 0; i < 4; i++)
#pragma unroll
        for (int j = 0; j < 4; j++) acc[i][j] = 0.f;
#pragma unroll 4
    for (int k = 0; k < 64; k++) {
        float4 w = *(const float4*)&sW[k * 64 + dg * 4];
#pragma unroll
        for (int i = 0; i < 4; i++) {
            float xv = sX[(ng + i * 16) * XPAD + k];
            acc[i][0] = fmaf(xv, w.x, acc[i][0]);
            acc[i][1] = fmaf(xv, w.y, acc[i][1]);
            acc[i][2] = fmaf(xv, w.z, acc[i][2]);
            acc[i][3] = fmaf(xv, w.w, acc[i][3]);
        }
    }
    float4 blv = *(const float4*)&bl[dg * 4];
#pragma unroll
    for (int i = 0; i < 4; i++) {
        int node = tile + ng + i * 16;
        if (node < N_NODES)
            *(float4*)&Qout[(size_t)node * 64 + dg * 4] =
                make_float4(acc[i][0] + blv.x, acc[i][1] + blv.y,
                            acc[i][2] + blv.z, acc[i][3] + blv.w);
    }
}

// ---------------- fused: LDS CSR + layer-0 aggregate + layer-1 xform ----------------
__global__ __launch_bounds__(256, 4) void k_fused1(
    const int* __restrict__ cnt, const int* __restrict__ ebuf,
    const __hip_bfloat16* __restrict__ Pb0, const float* __restrict__ Wl,
    const float* __restrict__ bl, const float* __restrict__ Wr,
    __hip_bfloat16* __restrict__ Pb1, float* __restrict__ H) {
    __shared__ float sW[64 * 64];
    __shared__ float sX[64 * XPAD];
    __shared__ unsigned short lcsr[BKT_CAP];
    __shared__ int nhist[BKT_NODES], sval[BKT_NODES], sexcl[BKT_NODES], ncur[BKT_NODES];
    int t = threadIdx.x;
    int tile = blockIdx.x * 64;
    // Wl prefetch issues early; hides behind CSR build + gather
    for (int i = t; i < 64 * 16; i += 256)
        ((float4*)sW)[i] = ((const float4*)Wl)[i];
    build_local_csr(blockIdx.x, cnt, ebuf, lcsr, nhist, sval, sexcl, ncur);
    // phase (a): dual-node aggregate per eighth-wave, H0 = relu(mean+Q0) -> sX
    int grp = t >> 3, sl = t & 7;
    int ln0 = grp * 2, ln1 = ln0 + 1;
    float mA[8], mB[8];
    agg2(sexcl[ln0], sval[ln0], sexcl[ln1], sval[ln1], sl, lcsr, Pb0, mA, mB);
    finish_row(tile + ln0, sl, H, mA, &sX[ln0 * XPAD]);
    finish_row(tile + ln1, sl, H, mB, &sX[ln1 * XPAD]);
    __syncthreads();
    // phase (b1): Pb1 = H0 @ Wl
    int dg = t & 15, ng = t >> 4;
    float acc[4][4];
#pragma unroll
    for (int i = 0; i < 4; i++)
#pragma unroll
        for (int j = 0; j < 4; j++) acc[i][j] = 0.f;
#pragma unroll 4
    for (int k = 0; k < 64; k++) {
        float4 w = *(const float4*)&sW[k * 64 + dg * 4];
#pragma unroll
        for (int i = 0; i < 4; i++) {
            float xv = sX[(ng + i * 16) * XPAD + k];
            acc[i][0] = fmaf(xv, w.x, acc[i][0]);
            acc[i][1] = fmaf(xv, w.y, acc[i][1]);
            acc[i][2] = fmaf(xv, w.z, acc[i][2]);
            acc[i][3] = fmaf(xv, w.w, acc[i][3]);
        }
    }
#pragma unroll
    for (int i = 0; i < 4; i++) {
        int node = tile + ng + i * 16;
        if (node < N_NODES) {
            union { ushort4 u; __hip_bfloat16 h[4]; } pk;
            pk.h[0] = __float2bfloat16(acc[i][0]);
            pk.h[1] = __float2bfloat16(acc[i][1]);
            pk.h[2] = __float2bfloat16(acc[i][2]);
            pk.h[3] = __float2bfloat16(acc[i][3]);
            *(ushort4*)&Pb1[(size_t)node * 64 + dg * 4] = pk.u;
        }
    }
    __syncthreads();
    for (int i = t; i < 64 * 16; i += 256)
        ((float4*)sW)[i] = ((const float4*)Wr)[i];
    __syncthreads();
    // phase (b2): H = Q1 = H0 @ Wr + bl
#pragma unroll
    for (int i = 0; i < 4; i++)
#pragma unroll
        for (int j = 0; j < 4; j++) acc[i][j] = 0.f;
#pragma unroll 4
    for (int k = 0; k < 64; k++) {
        float4 w = *(const float4*)&sW[k * 64 + dg * 4];
#pragma unroll
        for (int i = 0; i < 4; i++) {
            float xv = sX[(ng + i * 16) * XPAD + k];
            acc[i][0] = fmaf(xv, w.x, acc[i][0]);
            acc[i][1] = fmaf(xv, w.y, acc[i][1]);
            acc[i][2] = fmaf(xv, w.z, acc[i][2]);
            acc[i][3] = fmaf(xv, w.w, acc[i][3]);
        }
    }
    float4 blv = *(const float4*)&bl[dg * 4];
#pragma unroll
    for (int i = 0; i < 4; i++) {
        int node = tile + ng + i * 16;
        if (node < N_NODES)
            *(float4*)&H[(size_t)node * 64 + dg * 4] =
                make_float4(acc[i][0] + blv.x, acc[i][1] + blv.y,
                            acc[i][2] + blv.z, acc[i][3] + blv.w);
    }
}

// ---------------- layer-1 aggregate + pooling (block = bucket = 64 nodes) ----------------
// v2: stage relu rows in LDS, then per-dim segmented sum (batch sorted) ->
// coalesced global atomics. Replaces 4096 8-way same-address LDS atomics/block.
__global__ __launch_bounds__(256, 4) void k_agg2_pool(
    const int* __restrict__ cnt, const int* __restrict__ ebuf,
    const __hip_bfloat16* __restrict__ Pb, const float* __restrict__ H,
    const int* __restrict__ batch, float* __restrict__ psum) {
    __shared__ float sPool[64 * 64];
    __shared__ unsigned short lcsr[BKT_CAP];
    __shared__ int nhist[BKT_NODES], sval[BKT_NODES], sexcl[BKT_NODES], ncur[BKT_NODES];
    __shared__ int sLg[64];
    int t = threadIdx.x;
    int nb = blockIdx.x * 64;
    int gmin = batch[nb];
    if (t < 64) {
        int node = nb + t;
        sLg[t] = batch[node < N_NODES ? node : (N_NODES - 1)] - gmin;
    }
    build_local_csr(blockIdx.x, cnt, ebuf, lcsr, nhist, sval, sexcl, ncur);
    int grp = t >> 3, sl = t & 7;
    int ln0 = grp * 2, ln1 = ln0 + 1;
    float mA[8], mB[8];
    agg2(sexcl[ln0], sval[ln0], sexcl[ln1], sval[ln1], sl, lcsr, Pb, mA, mB);
    finish_row(nb + ln0, sl, H, mA, &sPool[ln0 * 64]);
    finish_row(nb + ln1, sl, H, mB, &sPool[ln1 * 64]);
    __syncthreads();
    // segmented per-dim sum over this bucket's 64 rows (batch sorted -> lg
    // non-decreasing). Each thread owns one dim x one 16-node quarter.
    int d = t & 63, q = t >> 6;
    int n0 = q * 16;
    float run = 0.f;
    int cur = sLg[n0];
    for (int n = n0; n < n0 + 16; n++) {
        int lg = sLg[n];
        if (lg != cur) {
            if (run != 0.f)
                atomicAdd(&psum[(size_t)(gmin + cur) * 64 + d], run);
            run = 0.f;
            cur = lg;
        }
        run += sPool[n * 64 + d];
    }
    if (run != 0.f)
        atomicAdd(&psum[(size_t)(gmin + cur) * 64 + d], run);
}

// ---------------- output projection ----------------
__device__ __forceinline__ int lower_bound_batch(const int* __restrict__ batch, int val) {
    int lo = 0, hi = N_NODES;
    while (lo < hi) {
        int mid = (lo + hi) >> 1;
        if (batch[mid] < val) lo = mid + 1; else hi = mid;
    }
    return lo;
}

__global__ __launch_bounds__(256) void k_out(
    const int* __restrict__ batch, const float* __restrict__ psum,
    const float* __restrict__ Wout, const float* __restrict__ bout,
    float* __restrict__ out) {
    int w = threadIdx.x >> 6, lane = threadIdx.x & 63;
    int g = blockIdx.x * 4 + w;
    if (g >= N_GRAPHS) return;
    int s0 = lower_bound_batch(batch, g);
    int s1 = lower_bound_batch(batch, g + 1);
    int cntg = s1 - s0;
    float inv = (cntg > 0) ? 1.0f / (float)cntg : 0.0f;
    float pooled = psum[(size_t)g * 64 + lane] * inv;
#pragma unroll
    for (int c = 0; c < N_CLASSES; c++) {
        float v = pooled * Wout[lane * N_CLASSES + c];
#pragma unroll
        for (int off = 32; off > 0; off >>= 1) v += __shfl_down(v, off, 64);
        if (lane == 0) out[(size_t)g * N_CLASSES + c] = v + bout[c];
    }
}

// ---------------- launch ----------------

extern "C" void kernel_launch(void* const* d_in, const int* in_sizes, int n_in,
                              void* d_out, int out_size, void* d_ws, size_t ws_size,
                              hipStream_t stream) {
    const int*   node_ids = (const int*)d_in[0];
    const int*   edge_idx = (const int*)d_in[1];   // [2, E] row-major
    const int*   batch    = (const int*)d_in[2];
    const float* emb      = (const float*)d_in[3];
    const float* Wl0      = (const float*)d_in[4];
    const float* bl0      = (const float*)d_in[5];
    const float* Wr0      = (const float*)d_in[6];
    const float* Wl1      = (const float*)d_in[7];
    const float* bl1      = (const float*)d_in[8];
    const float* Wr1      = (const float*)d_in[9];
    const float* Wout     = (const float*)d_in[10];
    const float* bout     = (const float*)d_in[11];
    float* out = (float*)d_out;

    const int* esrc = edge_idx;
    const int* edst = edge_idx + N_EDGES;

    // workspace layout
    __hip_bfloat16* Pb0 = (__hip_bfloat16*)d_ws;              // N*64 bf16
    __hip_bfloat16* Pb1 = Pb0 + (size_t)N_NODES * 64;         // N*64 bf16
    float* H = (float*)(Pb1 + (size_t)N_NODES * 64);          // N*64 f32
    int* ebuf = (int*)(H + (size_t)N_NODES * 64);             // NB*CAP ints
    int* cnt = ebuf + (size_t)NB_BKT * BKT_CAP;               // NB*CNT_STRIDE ints
    float* psum = (float*)(cnt + (size_t)NB_BKT * CNT_STRIDE); // G*64 floats (contiguous w/ cnt)

    const int BLK = 256;

    // one memset zeroes padded bucket counters + pool accumulators (contiguous)
    hipMemsetAsync(cnt, 0, (NB_BKT * CNT_STRIDE + N_GRAPHS * 64) * sizeof(int), stream);

    // combo: bucket multi-split (196 blocks) + layer-0 xform (782 blocks)
    k_combo<<<EB_BLOCKS + XFORM_BLOCKS, BLK, 0, stream>>>(
        esrc, edst, cnt, ebuf, node_ids, emb, Wl0, bl0, Wr0, Pb0, H);

    // fused layer-0 aggregate (LDS CSR) + layer-1 transform
    k_fused1<<<XFORM_BLOCKS, BLK, 0, stream>>>(cnt, ebuf, Pb0, Wl1, bl1, Wr1, Pb1, H);

    // layer-1 aggregate (LDS CSR) fused with graph pooling
    k_agg2_pool<<<NB_BKT, BLK, 0, stream>>>(cnt, ebuf, Pb1, H, batch, psum);

    // output projection
    k_out<<<(N_GRAPHS + 3) / 4, BLK, 0, stream>>>(batch, psum, Wout, bout, out);
}